// Round 16
// baseline (90.338 us; speedup 1.0000x reference)
//
#include <hip/hip_runtime.h>
#include <hip/hip_bf16.h>
#include <math.h>

using short8 = __attribute__((ext_vector_type(8))) short;
using f32x4  = __attribute__((ext_vector_type(4))) float;
using fv4    = __attribute__((ext_vector_type(4))) float;

#define EMB 768
#define CD  64
#define NSCEN 19
#define KSTEPS 24            // 768 / 32
#define NCHUNKS (25 * 4)     // (24 emb + 1 bag) k-steps x 4 col-tiles, 512 bf16 each
#define GB 8192              // ushorts per LDS B group-buffer (16 KB = 4 k-steps)
#define BM 128               // rows per block

__device__ __forceinline__ ushort f2bf(float x) {
    unsigned u = __float_as_uint(x);
    u += 0x7FFFu + ((u >> 16) & 1u);   // RNE
    return (ushort)(u >> 16);
}

// packed f32x2 -> bf16x2 (v_cvt_pk_bf16_f32)
__device__ __forceinline__ uint cvt2(float x, float y) {
    __hip_bfloat162 h = __float22bfloat162_rn(make_float2(x, y));
    union { __hip_bfloat162 h; uint u; } c;
    c.h = h;
    return c.u;
}

// Pre-fragment B = [W1(768x64) ; P(32x64)] into bf16 wave-chunks of 512 elems:
// chunk c = ks*4+ct; element r = lane*8+j  <->  B[k = ks*32+(lane>>4)*8+j][col = ct*16+(lane&15)]
__global__ void prep_W1T(const float* __restrict__ table,
                         const float* __restrict__ W1,
                         ushort* __restrict__ W1T) {
    int e0 = (blockIdx.x * 256 + threadIdx.x) * 4;   // grid 50x256
    if (e0 >= NCHUNKS * 512) return;
    int chunk = e0 >> 9, r = e0 & 511;
    int lane = r >> 3, j0 = r & 7;
    int ks = chunk >> 2, ct = chunk & 3;
    int col = ct * 16 + (lane & 15);
    int kbase = ks * 32 + ((lane >> 4) << 3) + j0;
    ushort res[4];
#pragma unroll
    for (int q = 0; q < 4; ++q) {
        int k = kbase + q;
        float v = 0.f;
        if (k < EMB) {
            v = W1[(size_t)k * CD + col];
        } else {
            int s = k - EMB;
            if (s < NSCEN) {
#pragma unroll
                for (int d = 0; d < 16; ++d)
                    v += table[s * 16 + d] * W1[(size_t)(EMB + s * 16 + d) * CD + col];
            }
        }
        res[q] = f2bf(v);
    }
    *(ushort4*)&W1T[e0] = make_ushort4(res[0], res[1], res[2], res[3]);
}

// 6 waves/SIMD target (3 blocks/CU): VGPR capped ~85, LDS 44.5 KB
__global__ __launch_bounds__(512, 6)
void scorer_mfma(const float* __restrict__ emb,
                 const int* __restrict__ ids,
                 const float* __restrict__ mask,
                 const ushort* __restrict__ W1T,
                 const float* __restrict__ b1,
                 const float* __restrict__ W2,
                 const float* __restrict__ b2,
                 float* __restrict__ out) {
    __shared__ __align__(16) ushort Bq[2][GB];       // 2 x 16 KB B group-buffers
    __shared__ __align__(16) ushort Pb[2048];        // bag B chunk (4 KB), loaded once
    __shared__ __align__(16) ushort bagb[8][16][32]; // per-wave bag rows (wave-local)

    const int t    = threadIdx.x;
    const int w    = t >> 6;       // wave 0..7, owns rows w*16..w*16+15
    const int lane = t & 63;
    const int lr   = lane & 15;
    const int lg   = lane >> 4;
    const int row0 = blockIdx.x * BM;

    // ================== startup vmem burst (before any VALU phase) ===============
    const int hrow = row0 + w * 16 + lr;
    const int*   idrow = ids  + (size_t)hrow * 32 + lg * 8;
    const float* mrow  = mask + (size_t)hrow * 32 + lg * 8;
    int4   iv0 = ((const int4*)idrow)[0],  iv1 = ((const int4*)idrow)[1];
    float4 mv0 = ((const float4*)mrow)[0], mv1 = ((const float4*)mrow)[1];

    const float* ap = emb + (size_t)(row0 + w * 16 + lr) * EMB + (lg << 3);
    fv4 aA[2], aB[2];
#define LOADA(dst, kks) do {                                   \
    const float* _p = ap + (kks) * 32;                         \
    dst[0] = *(const fv4*)(_p);                                \
    dst[1] = *(const fv4*)(_p + 4);                            \
} while (0)
    LOADA(aA, 0);   // first A k-step in flight during histogram

    uint4 fA, fB;   // fill staging: 32 B/thread (16 KB group / 512 threads)
#define ISSUE_FILL(g) do {                                                    \
    const uint* _g = (const uint*)((const char*)W1T + (size_t)(g) * 16384);  \
    fA = *(const uint4*)(_g + (t)       * 4);                                \
    fB = *(const uint4*)(_g + (t + 512) * 4);                                \
} while (0)
#define WRITE_FILL(bufi) do {                                                \
    uint* _l = (uint*)&Bq[bufi][0];                                          \
    *(uint4*)(_l + (t)       * 4) = fA;                                      \
    *(uint4*)(_l + (t + 512) * 4) = fB;                                      \
} while (0)
    ISSUE_FILL(0);   // group 0 (k-steps 0-3) in flight during histogram
    uint4 pv;
    if (t < 256) pv = *(const uint4*)((const char*)W1T + 98304 + t * 16);  // bag chunk

    // ================== histogram: pure VALU, in-register, no atomics ============
    float bin[NSCEN];
#pragma unroll
    for (int s = 0; s < NSCEN; ++s) bin[s] = 0.f;
    float cnt = 0.f;
#define HSLOT(idv, mvv) do {                                   \
    cnt += mvv;                                                \
    _Pragma("unroll")                                          \
    for (int s = 0; s < NSCEN; ++s)                            \
        bin[s] += (idv == s) ? mvv : 0.f;                      \
} while (0)
    HSLOT(iv0.x, mv0.x); HSLOT(iv0.y, mv0.y); HSLOT(iv0.z, mv0.z); HSLOT(iv0.w, mv0.w);
    HSLOT(iv1.x, mv1.x); HSLOT(iv1.y, mv1.y); HSLOT(iv1.z, mv1.z); HSLOT(iv1.w, mv1.w);
#undef HSLOT
    cnt += __shfl_xor(cnt, 16);
    cnt += __shfl_xor(cnt, 32);
#pragma unroll
    for (int s = 0; s < NSCEN; ++s) {
        bin[s] += __shfl_xor(bin[s], 16);
        bin[s] += __shfl_xor(bin[s], 32);
    }
    {
        float rc = 1.0f / fmaxf(cnt, 1.0f);
        if (lane < 16) {   // lane l writes row w*16+l (wave-local)
            uint u[16];
#pragma unroll
            for (int p = 0; p < 9; ++p) u[p] = cvt2(bin[2 * p] * rc, bin[2 * p + 1] * rc);
            u[9] = cvt2(bin[18] * rc, 0.f);
#pragma unroll
            for (int p = 10; p < 16; ++p) u[p] = 0u;
            ushort* bp = &bagb[w][lane][0];
#pragma unroll
            for (int q = 0; q < 4; ++q)
                *(uint4*)(bp + q * 8) = make_uint4(u[4 * q], u[4 * q + 1], u[4 * q + 2], u[4 * q + 3]);
        }
    }

    WRITE_FILL(0);                               // Bq0 <- group 0
    if (t < 256) *(uint4*)((char*)Pb + t * 16) = pv;   // Pb <- bag chunk
    ISSUE_FILL(1);                               // group 1
    __syncthreads();   // Bq0 + Pb ready

    // ================== MFMA stream ==============================================
    f32x4 acc[4];
#pragma unroll
    for (int j = 0; j < 4; ++j) acc[j] = (f32x4)0.f;

    short8 bqr[4];
#define LDSB(bufi, ksl) do {                                   \
    const ushort* _l = &Bq[bufi][(ksl) * 2048 + lane * 8];     \
    bqr[0] = *(const short8*)(_l);                             \
    bqr[1] = *(const short8*)(_l + 512);                       \
    bqr[2] = *(const short8*)(_l + 1024);                      \
    bqr[3] = *(const short8*)(_l + 1536);                      \
} while (0)

#define STEP(areg) do {                                                     \
    union { uint u[4]; short8 s; } _c;                                      \
    _c.u[0] = cvt2(areg[0][0], areg[0][1]);                                 \
    _c.u[1] = cvt2(areg[0][2], areg[0][3]);                                 \
    _c.u[2] = cvt2(areg[1][0], areg[1][1]);                                 \
    _c.u[3] = cvt2(areg[1][2], areg[1][3]);                                 \
    acc[0] = __builtin_amdgcn_mfma_f32_16x16x32_bf16(_c.s, bqr[0], acc[0], 0, 0, 0); \
    acc[1] = __builtin_amdgcn_mfma_f32_16x16x32_bf16(_c.s, bqr[1], acc[1], 0, 0, 0); \
    acc[2] = __builtin_amdgcn_mfma_f32_16x16x32_bf16(_c.s, bqr[2], acc[2], 0, 0, 0); \
    acc[3] = __builtin_amdgcn_mfma_f32_16x16x32_bf16(_c.s, bqr[3], acc[3], 0, 0, 0); \
} while (0)

// 4 emb k-steps from buffer bufi, global steps qs..qs+3 (A ping-pong depth-1)
#define GROUP(bufi, qs) do {                                                \
    _Pragma("unroll")                                                       \
    for (int _ksl = 0; _ksl < 4; ++_ksl) {                                  \
        const int _ks = (qs) + _ksl;                                        \
        LDSB(bufi, _ksl);                                                   \
        if ((_ks & 1) == 0) {                                               \
            if (_ks + 1 <= 23) LOADA(aB, _ks + 1);                          \
            STEP(aA);                                                       \
        } else {                                                            \
            if (_ks + 1 <= 23) LOADA(aA, _ks + 1);                          \
            STEP(aB);                                                       \
        }                                                                   \
    }                                                                       \
} while (0)

    // g=0..5: compute group g from Bq[g&1]; fill Bq[(g+1)&1] with group g+1
    WRITE_FILL(1); ISSUE_FILL(2);
    GROUP(0, 0);
    __syncthreads();

    WRITE_FILL(0); ISSUE_FILL(3);
    GROUP(1, 4);
    __syncthreads();

    WRITE_FILL(1); ISSUE_FILL(4);
    GROUP(0, 8);
    __syncthreads();

    WRITE_FILL(0); ISSUE_FILL(5);
    GROUP(1, 12);
    __syncthreads();

    WRITE_FILL(1);
    GROUP(0, 16);
    __syncthreads();

    GROUP(1, 20);
    {   // bag k-step: A from bagb (wave-local), B = Pb
        short8 ab = *(const short8*)&bagb[w][lr][lg << 3];
        const ushort* _l = &Pb[lane * 8];
        short8 p0 = *(const short8*)(_l);
        short8 p1 = *(const short8*)(_l + 512);
        short8 p2 = *(const short8*)(_l + 1024);
        short8 p3 = *(const short8*)(_l + 1536);
        acc[0] = __builtin_amdgcn_mfma_f32_16x16x32_bf16(ab, p0, acc[0], 0, 0, 0);
        acc[1] = __builtin_amdgcn_mfma_f32_16x16x32_bf16(ab, p1, acc[1], 0, 0, 0);
        acc[2] = __builtin_amdgcn_mfma_f32_16x16x32_bf16(ab, p2, acc[2], 0, 0, 0);
        acc[3] = __builtin_amdgcn_mfma_f32_16x16x32_bf16(ab, p3, acc[3], 0, 0, 0);
    }

    // ================== epilogue: bias + relu + dot(W2) + tanh ===================
    float b1v[4], w2v[4];
#pragma unroll
    for (int ct = 0; ct < 4; ++ct) {
        int c = ct * 16 + lr;
        b1v[ct] = b1[c];
        w2v[ct] = W2[c];
    }
    const float b2v = b2[0];
#pragma unroll
    for (int r = 0; r < 4; ++r) {
        float p = 0.f;
#pragma unroll
        for (int ct = 0; ct < 4; ++ct) {
            float h = acc[ct][r] + b1v[ct];
            p += fmaxf(h, 0.f) * w2v[ct];
        }
        p += __shfl_xor(p, 1);
        p += __shfl_xor(p, 2);
        p += __shfl_xor(p, 4);
        p += __shfl_xor(p, 8);
        if (lr == 0)
            out[row0 + w * 16 + (lg << 2) + r] = tanhf(p + b2v);
    }
#undef ISSUE_FILL
#undef WRITE_FILL
#undef LOADA
#undef LDSB
#undef STEP
#undef GROUP
}

extern "C" void kernel_launch(void* const* d_in, const int* in_sizes, int n_in,
                              void* d_out, int out_size, void* d_ws, size_t ws_size,
                              hipStream_t stream) {
    const float* emb   = (const float*)d_in[0];
    const int*   ids   = (const int*)d_in[1];
    const float* mask  = (const float*)d_in[2];
    const float* table = (const float*)d_in[3];
    const float* W1    = (const float*)d_in[4];
    const float* b1    = (const float*)d_in[5];
    const float* W2    = (const float*)d_in[6];
    const float* b2    = (const float*)d_in[7];
    float* out  = (float*)d_out;
    ushort* W1T = (ushort*)d_ws;   // 51200 bf16 = 100 KB

    prep_W1T<<<50, 256, 0, stream>>>(table, W1, W1T);
    const int nblocks = out_size / BM;   // 1024
    scorer_mfma<<<nblocks, 512, 0, stream>>>(emb, ids, mask, W1T, b1, W2, b2, out);
}